// Round 9
// baseline (201967.957 us; speedup 1.0000x reference)
//
#include <hip/hip_runtime.h>

// RNNDetector: 2-layer LSTM (H=64), T=262144 sequential steps + 16-wide head.
// ROUND 8 DECISIVE RESULT: weights in hard physical VGPRs (zero weight loads
// per step, by construction) -> time UNCHANGED at ~1815 cyc/step. The 8-round
// invariant is the PER-STEP BARRIER: __syncthreads() makes the compiler emit
// s_waitcnt vmcnt(0) expcnt(0) lgkmcnt(0) before s_barrier, draining the y
// prefetch load (~200-900 cyc) and the head's global_store (~300+ cyc) every
// step, on every wave. THIS ROUND: hand-rolled barrier that waits ONLY on
// LDS (s_waitcnt lgkmcnt(0); s_barrier) — h state transits only through LDS,
// so that is all correctness needs. Global loads/stores now ride across
// barriers; the depth-4 y queue finally functions; out stores fire-and-forget.
// Everything else is R8 verbatim (weights resident in v[100:163] L0 /
// v[100:227] L1; lane (q,r,g) K-shard; shard-reduce xor1/xor2; gate algebra
// xor8/xor4; head reduce; pipeline s: h0(s), h1(s-1), out(s-2)).

constexpr int T = 262144;

typedef float v4 __attribute__((ext_vector_type(4)));

__device__ __forceinline__ float rcp_f(float x) { return __builtin_amdgcn_rcpf(x); }

// LDS-only barrier: make ds_writes visible, do NOT drain global traffic.
#define BARRIER() asm volatile("s_waitcnt lgkmcnt(0)\n\ts_barrier" ::: "memory")

// ---- asm text generators ----
#define FM(acc, h, w) "v_fmac_f32 v" #acc ", v" #h ", v" #w "\n\t"
#define C0(h, w0, w1, w2, w3) FM(32,h,w0) FM(33,h,w1) FM(34,h,w2) FM(35,h,w3)
#define C1(h, w0, w1, w2, w3) FM(48,h,w0) FM(49,h,w1) FM(50,h,w2) FM(51,h,w3)
#define GL(r0, r1, off) \
  "global_load_dwordx4 v[" #r0 ":" #r1 "], %0, off offset:" #off "\n\t"
#define DR(r0, r1, off) "ds_read_b128 v[" #r0 ":" #r1 "], %4 offset:" #off "\n\t"

// R2/R5-validated gate algebra, shuffle distances 8 (r^2) and 4 (r^1).
__device__ __forceinline__ float gate_update(float pre, int r, float& c) {
  const bool isG = (r == 2);
  float z  = fminf(fmaxf(pre * (isG ? 2.f : 1.f), -30.f), 30.f);
  float ex = __expf(-z);
  float a  = (isG ? (1.f - ex) : 1.f) * rcp_f(1.f + ex);
  float b2 = __shfl_xor(a, 8);          // partner gate r^2
  float fo = (r & 2) ? b2 : a;
  float m1 = (r & 1) ? fo : a;
  float m2 = (r & 1) ? c  : b2;
  float p  = m1 * m2;
  float cn = p + __shfl_xor(p, 4);      // i*g + f*c in all 4 lanes
  c = cn;
  float zz = fminf(fmaxf(cn, -15.f), 15.f);
  float e2 = __expf(-2.f * zz);
  float th = (1.f - e2) * rcp_f(1.f + e2);
  float oo = (r & 2) ? a : b2;          // r==3 holds o
  return oo * th;
}

// ---- prepass: pack per-lane-contiguous weight slices (f32) into d_ws ----
__global__ void pack_slices(const float* __restrict__ Whh0,
                            const float* __restrict__ Wih1,
                            const float* __restrict__ Whh1,
                            float* __restrict__ ws) {
  int i = blockIdx.x * 256 + threadIdx.x;          // 0..49151
  if (i < 16384) {
    int l = i >> 6, rem = i & 63, k = rem >> 2, rr = rem & 3;
    int q = l & 3, r = (l >> 2) & 3, g = l >> 4;
    ws[i] = Whh0[(r * 64 + 4 * g + rr) * 64 + 16 * q + k];
  } else {
    int i2 = i - 16384;
    int l = i2 >> 7, rem = i2 & 127, k = rem >> 2, rr = rem & 3;
    int q = l & 3, r = (l >> 2) & 3, g = l >> 4;
    const float* M = (q < 2) ? Wih1 : Whh1;
    ws[i] = M[(r * 64 + 4 * g + rr) * 64 + 32 * (q & 1) + k];
  }
}

__global__ __launch_bounds__(512) void rnn_fused(
    const float* __restrict__ y,
    const float* __restrict__ Wih0, const float* __restrict__ bih0,
    const float* __restrict__ bhh0,
    const float* __restrict__ bih1, const float* __restrict__ bhh1,
    const float* __restrict__ Wlin, const float* __restrict__ blin,
    const float* __restrict__ ws,              // packed per-lane slices
    float* __restrict__ out)
{
  const int tid  = threadIdx.x;
  const bool isL1 = tid >= 256;
  const int l  = tid & 255;
  const int q  = l & 3;                 // k-shard
  const int r  = (l >> 2) & 3;          // gate 0=i 1=f 2=g 3=o
  const int g  = l >> 4;                // element group 0..15
  const int e  = 4 * g + q;             // this lane's element
  const int jrow = r * 64 + e;          // bias row

  // LDS: h0[2][64] @0, h1[2][64] @136 (8-float skew; 0 conflicts, R5-verified)
  __shared__ __align__(16) float smem[272];
  if (tid < 272) smem[tid] = 0.f;
  __syncthreads();

  if (!isL1) {
    // ===== layer 0 (+ head): weights -> v[100:163], ONCE =====
    unsigned long long wbase = (unsigned long long)(uintptr_t)(ws + l * 64);
    asm volatile(
      GL(100,103,0)   GL(104,107,16)  GL(108,111,32)  GL(112,115,48)
      GL(116,119,64)  GL(120,123,80)  GL(124,127,96)  GL(128,131,112)
      GL(132,135,128) GL(136,139,144) GL(140,143,160) GL(144,147,176)
      GL(148,151,192) GL(152,155,208) GL(156,159,224) GL(160,163,240)
      "s_waitcnt vmcnt(0)\n\t"
      :: "v"(wbase)
      : "v100","v101","v102","v103","v104","v105","v106","v107",
        "v108","v109","v110","v111","v112","v113","v114","v115",
        "v116","v117","v118","v119","v120","v121","v122","v123",
        "v124","v125","v126","v127","v128","v129","v130","v131",
        "v132","v133","v134","v135","v136","v137","v138","v139",
        "v140","v141","v142","v143","v144","v145","v146","v147",
        "v148","v149","v150","v151","v152","v153","v154","v155",
        "v156","v157","v158","v159","v160","v161","v162","v163","memory");

    float bb  = bih0[jrow] + bhh0[jrow];
    float wi0 = Wih0[jrow];
    const int hm = tid >> 4, hk = tid & 15;       // head mapping (R4/R5-verified)
    v4 WL = *((const v4*)(Wlin + hm * 64) + hk);
    float bl = (hk == 0) ? blin[hm] : 0.f;
    const float* hbase = smem + 16 * q;           // h0 chunk base
    const float* hhead = smem + 136 + 4 * hk;     // head h1 slice
    float c = 0.f;
    float yq0 = y[0], yq1 = y[1], yq2 = y[2], yq3 = y[3];

    #pragma unroll 1
    for (int s = 0; s < T + 2; ++s) {
      const int cur = s & 1, nxt = cur ^ 1;
      // ---- head: out(s-2) from h1[cur] ----
      if (s >= 2) {
        v4 hh = *(const v4*)(hhead + cur * 64);
        v4 tt = WL * hh;
        float p2 = (tt.x + tt.y) + (tt.z + tt.w);
        p2 += __shfl_xor(p2, 1);
        p2 += __shfl_xor(p2, 2);
        p2 += __shfl_xor(p2, 4);
        p2 += __shfl_xor(p2, 8);
        if (hk == 0) out[(s - 2) * 16 + hm] = p2 + bl;   // fire-and-forget
      }
      // ---- layer 0: h0(s) from h0[cur], y[s] ----
      if (s < T) {
        float y_nxt = (s + 4 < T) ? y[s + 4] : 0.f;   // rides across barriers now
        unsigned haddr = (unsigned)(uintptr_t)(hbase + cur * 64);
        float a0, a1, a2, a3;
        asm volatile(
          "v_mov_b32 v32, 0\n\t" "v_mov_b32 v33, 0\n\t"
          "v_mov_b32 v34, 0\n\t" "v_mov_b32 v35, 0\n\t"
          DR(16,19,0) DR(20,23,16) DR(24,27,32) DR(28,31,48)
          "s_waitcnt lgkmcnt(0)\n\t"
          C0(16,100,101,102,103) C0(17,104,105,106,107)
          C0(18,108,109,110,111) C0(19,112,113,114,115)
          C0(20,116,117,118,119) C0(21,120,121,122,123)
          C0(22,124,125,126,127) C0(23,128,129,130,131)
          C0(24,132,133,134,135) C0(25,136,137,138,139)
          C0(26,140,141,142,143) C0(27,144,145,146,147)
          C0(28,148,149,150,151) C0(29,152,153,154,155)
          C0(30,156,157,158,159) C0(31,160,161,162,163)
          "v_mov_b32 %0, v32\n\t" "v_mov_b32 %1, v33\n\t"
          "v_mov_b32 %2, v34\n\t" "v_mov_b32 %3, v35\n\t"
          : "=v"(a0), "=v"(a1), "=v"(a2), "=v"(a3)
          : "v"(haddr)
          : "v16","v17","v18","v19","v20","v21","v22","v23",
            "v24","v25","v26","v27","v28","v29","v30","v31",
            "v32","v33","v34","v35","memory");
        a0 += __shfl_xor(a0, 1); a1 += __shfl_xor(a1, 1);
        a2 += __shfl_xor(a2, 1); a3 += __shfl_xor(a3, 1);
        a0 += __shfl_xor(a0, 2); a1 += __shfl_xor(a1, 2);
        a2 += __shfl_xor(a2, 2); a3 += __shfl_xor(a3, 2);
        float s1 = (q & 1) ? a1 : a0;
        float s2 = (q & 1) ? a3 : a2;
        float pre = ((q & 2) ? s2 : s1) + fmaf(yq0, wi0, bb);
        float h = gate_update(pre, r, c);
        if (r == 3) smem[nxt * 64 + e] = h;
        yq0 = yq1; yq1 = yq2; yq2 = yq3; yq3 = y_nxt;
      }
      BARRIER();     // LDS-only: no vmcnt drain
    }
  } else {
    // ===== layer 1: weights -> v[100:227], ONCE =====
    unsigned long long wbase =
        (unsigned long long)(uintptr_t)(ws + 16384 + l * 128);
    asm volatile(
      GL(100,103,0)   GL(104,107,16)  GL(108,111,32)  GL(112,115,48)
      GL(116,119,64)  GL(120,123,80)  GL(124,127,96)  GL(128,131,112)
      GL(132,135,128) GL(136,139,144) GL(140,143,160) GL(144,147,176)
      GL(148,151,192) GL(152,155,208) GL(156,159,224) GL(160,163,240)
      GL(164,167,256) GL(168,171,272) GL(172,175,288) GL(176,179,304)
      GL(180,183,320) GL(184,187,336) GL(188,191,352) GL(192,195,368)
      GL(196,199,384) GL(200,203,400) GL(204,207,416) GL(208,211,432)
      GL(212,215,448) GL(216,219,464) GL(220,223,480) GL(224,227,496)
      "s_waitcnt vmcnt(0)\n\t"
      :: "v"(wbase)
      : "v100","v101","v102","v103","v104","v105","v106","v107",
        "v108","v109","v110","v111","v112","v113","v114","v115",
        "v116","v117","v118","v119","v120","v121","v122","v123",
        "v124","v125","v126","v127","v128","v129","v130","v131",
        "v132","v133","v134","v135","v136","v137","v138","v139",
        "v140","v141","v142","v143","v144","v145","v146","v147",
        "v148","v149","v150","v151","v152","v153","v154","v155",
        "v156","v157","v158","v159","v160","v161","v162","v163",
        "v164","v165","v166","v167","v168","v169","v170","v171",
        "v172","v173","v174","v175","v176","v177","v178","v179",
        "v180","v181","v182","v183","v184","v185","v186","v187",
        "v188","v189","v190","v191","v192","v193","v194","v195",
        "v196","v197","v198","v199","v200","v201","v202","v203",
        "v204","v205","v206","v207","v208","v209","v210","v211",
        "v212","v213","v214","v215","v216","v217","v218","v219",
        "v220","v221","v222","v223","v224","v225","v226","v227","memory");

    float bb = bih1[jrow] + bhh1[jrow];
    const float* hbase = ((q < 2) ? smem : smem + 136) + 32 * (q & 1);
    float c = 0.f;

    #pragma unroll 1
    for (int s = 0; s < T + 2; ++s) {
      const int cur = s & 1, nxt = cur ^ 1;
      if (s >= 1 && s <= T) {
        unsigned haddr = (unsigned)(uintptr_t)(hbase + cur * 64);
        float a0, a1, a2, a3;
        asm volatile(
          "v_mov_b32 v48, 0\n\t" "v_mov_b32 v49, 0\n\t"
          "v_mov_b32 v50, 0\n\t" "v_mov_b32 v51, 0\n\t"
          DR(16,19,0)  DR(20,23,16) DR(24,27,32) DR(28,31,48)
          DR(32,35,64) DR(36,39,80) DR(40,43,96) DR(44,47,112)
          "s_waitcnt lgkmcnt(0)\n\t"
          C1(16,100,101,102,103) C1(17,104,105,106,107)
          C1(18,108,109,110,111) C1(19,112,113,114,115)
          C1(20,116,117,118,119) C1(21,120,121,122,123)
          C1(22,124,125,126,127) C1(23,128,129,130,131)
          C1(24,132,133,134,135) C1(25,136,137,138,139)
          C1(26,140,141,142,143) C1(27,144,145,146,147)
          C1(28,148,149,150,151) C1(29,152,153,154,155)
          C1(30,156,157,158,159) C1(31,160,161,162,163)
          C1(32,164,165,166,167) C1(33,168,169,170,171)
          C1(34,172,173,174,175) C1(35,176,177,178,179)
          C1(36,180,181,182,183) C1(37,184,185,186,187)
          C1(38,188,189,190,191) C1(39,192,193,194,195)
          C1(40,196,197,198,199) C1(41,200,201,202,203)
          C1(42,204,205,206,207) C1(43,208,209,210,211)
          C1(44,212,213,214,215) C1(45,216,217,218,219)
          C1(46,220,221,222,223) C1(47,224,225,226,227)
          "v_mov_b32 %0, v48\n\t" "v_mov_b32 %1, v49\n\t"
          "v_mov_b32 %2, v50\n\t" "v_mov_b32 %3, v51\n\t"
          : "=v"(a0), "=v"(a1), "=v"(a2), "=v"(a3)
          : "v"(haddr)
          : "v16","v17","v18","v19","v20","v21","v22","v23",
            "v24","v25","v26","v27","v28","v29","v30","v31",
            "v32","v33","v34","v35","v36","v37","v38","v39",
            "v40","v41","v42","v43","v44","v45","v46","v47",
            "v48","v49","v50","v51","memory");
        a0 += __shfl_xor(a0, 1); a1 += __shfl_xor(a1, 1);
        a2 += __shfl_xor(a2, 1); a3 += __shfl_xor(a3, 1);
        a0 += __shfl_xor(a0, 2); a1 += __shfl_xor(a1, 2);
        a2 += __shfl_xor(a2, 2); a3 += __shfl_xor(a3, 2);
        float s1 = (q & 1) ? a1 : a0;
        float s2 = (q & 1) ? a3 : a2;
        float pre = ((q & 2) ? s2 : s1) + bb;
        float h = gate_update(pre, r, c);
        if (r == 3) smem[136 + nxt * 64 + e] = h;
      }
      BARRIER();     // LDS-only: no vmcnt drain
    }
  }
}

extern "C" void kernel_launch(void* const* d_in, const int* in_sizes, int n_in,
                              void* d_out, int out_size, void* d_ws, size_t ws_size,
                              hipStream_t stream) {
  const float* y    = (const float*)d_in[0];
  const float* Wih0 = (const float*)d_in[1];
  const float* Whh0 = (const float*)d_in[2];
  const float* bih0 = (const float*)d_in[3];
  const float* bhh0 = (const float*)d_in[4];
  const float* Wih1 = (const float*)d_in[5];
  const float* Whh1 = (const float*)d_in[6];
  const float* bih1 = (const float*)d_in[7];
  const float* bhh1 = (const float*)d_in[8];
  const float* Wlin = (const float*)d_in[9];
  const float* blin = (const float*)d_in[10];
  float* ws = (float*)d_ws;                      // 49152 floats = 192KB

  pack_slices<<<dim3(192), dim3(256), 0, stream>>>(Whh0, Wih1, Whh1, ws);
  rnn_fused<<<dim3(1), dim3(512), 0, stream>>>(
      y, Wih0, bih0, bhh0, bih1, bhh1, Wlin, blin, ws, (float*)d_out);
}

// Round 11
// 170521.436 us; speedup vs baseline: 1.1844x; 1.1844x over previous
//
#include <hip/hip_runtime.h>

// RNNDetector: 2-layer LSTM (H=64), T=262144 sequential steps + 16-wide head.
// ROUND 9 DISCOVERY: rocprof VGPR_Count is in GRANULES OF 2 (R8 hard-wired
// v227, ran correct, reported 116 = 232 actual). Weights were register-
// resident since R2 — residency/L2 theories were counter-unit artifacts.
// The 9-round ~1850cyc/step invariant is the per-CU LDS PIPE: ~156 LDS
// instrs/step (b128 reads + __shfl_xor = ds_swizzle/bpermute are LDS ops!).
// THIS ROUND cuts LDS instrs ~3.5x: (1) h state packed f16 -> half the
// reads; (2) v_dot2_f32_f16 (2 MAC/instr, f16 weights via prepass);
// (3) ALL cross-lane via quad_perm DPP (VALU, zero LDS): no gate shuffles
// (wave0 owns all 4 gates per lane), head reduce via DPP xor1/xor2.
// R10 COMPILE FIX: weight regs are ext_vector_type(4) (u4), NOT the HIP
// uint4 struct — struct operands lower to unsupported indirect asm ties.
// 3 waves: w0 = L0 (4 gates/lane, no exchange) ; w1 = L1 gates i,f ;
// w2 = L1 gates g,o + c1/h1 update (i,f via 1 LDS dword, 2 barriers/step).
// Pipeline: step s: h0(s) [w0], L1 gates(s-1) [w1,w2 ph1], h1(s-1) [w2 ph2],
// out(s-2) [w1 ph2]. h double-buffered; barriers are LDS-only (lgkmcnt).

constexpr int T = 262144;

typedef _Float16 h2v __attribute__((ext_vector_type(2)));
typedef unsigned u4 __attribute__((ext_vector_type(4)));

__device__ __forceinline__ float rcp_f(float x) { return __builtin_amdgcn_rcpf(x); }

#define BARRIER() asm volatile("s_waitcnt lgkmcnt(0)\n\ts_barrier" ::: "memory")

// packed-f16 dot2: acc += w.lo*h.lo + w.hi*h.hi (f32 accumulate)
static __device__ __forceinline__ float fd(unsigned w, unsigned h, float acc) {
#if __has_builtin(__builtin_amdgcn_fdot2)
  return __builtin_amdgcn_fdot2(__builtin_bit_cast(h2v, w),
                                __builtin_bit_cast(h2v, h), acc, false);
#else
  h2v a = __builtin_bit_cast(h2v, w), b = __builtin_bit_cast(h2v, h);
  acc = fmaf((float)a.x, (float)b.x, acc);
  acc = fmaf((float)a.y, (float)b.y, acc);
  return acc;
#endif
}

#define DP4(acc, W, H) { acc = fd((W).x, (H).x, acc); acc = fd((W).y, (H).y, acc); \
                         acc = fd((W).z, (H).z, acc); acc = fd((W).w, (H).w, acc); }

// quad_perm DPP cross-lane (pure VALU, no LDS): xor1 = 0xB1, xor2 = 0x4E
#define DPPX1(x) __builtin_bit_cast(float, __builtin_amdgcn_mov_dpp(            \
                    __builtin_bit_cast(int, (x)), 0xB1, 0xF, 0xF, true))
#define DPPX2(x) __builtin_bit_cast(float, __builtin_amdgcn_mov_dpp(            \
                    __builtin_bit_cast(int, (x)), 0x4E, 0xF, 0xF, true))

__device__ __forceinline__ float sigf(float x) {
  float z = fminf(fmaxf(x, -30.f), 30.f);
  return rcp_f(1.f + __expf(-z));
}
__device__ __forceinline__ float tanhf_(float x) {
  float z = fminf(fmaxf(x, -15.f), 15.f);
  float e2 = __expf(-2.f * z);
  return (1.f - e2) * rcp_f(1.f + e2);
}

// f32 -> f16 RNE (weights |w| < ~0.7: no overflow; flush sub-6e-5 to 0)
__device__ unsigned f16rne(float f) {
  unsigned u = __float_as_uint(f);
  unsigned s = (u >> 16) & 0x8000u;
  int e = (int)((u >> 23) & 0xff) - 127;
  unsigned m = u & 0x7fffffu;
  if (e < -14) return s;
  unsigned h = s | (unsigned)((e + 15) << 10) | (m >> 13);
  unsigned rem = m & 0x1fffu;
  h += (rem > 0x1000u) || (rem == 0x1000u && (h & 1u));
  return h;
}

// ---- prepass: pack f16 weights, per-(wave,lane)-contiguous ----
// ws dwords [0,24576): wave w, lane l, dword d: ws[(w*64+l)*128 + d]
//   w0: d = gate r(2b)<<5 | kpair(5b): Whh0[r*64+l][2kp,2kp+1]
//   w1: d = gsel<<6 | dk: row = gsel*64+l (i,f); dk<32 -> Wih1[row][2dk..],
//       dk>=32 -> Whh1[row][2(dk-32)..]
//   w2: same, row = 128 + gsel*64 + l (g,o)
// [24576,25088): head: lane l (m=l>>2,kq=l&3), d=0..7: Wlin[m][kq*16+2d..]
__global__ void pack_w(const float* __restrict__ Whh0,
                       const float* __restrict__ Wih1,
                       const float* __restrict__ Whh1,
                       const float* __restrict__ Wlin,
                       unsigned* __restrict__ ws) {
  int i = blockIdx.x * 256 + threadIdx.x;
  if (i >= 25088) return;
  float v0, v1;
  if (i < 24576) {
    int w = i >> 13, rem = i & 8191, l = rem >> 7, d = rem & 127;
    if (w == 0) {
      int r = d >> 5, kp = d & 31, row = r * 64 + l;
      v0 = Whh0[row * 64 + 2 * kp]; v1 = Whh0[row * 64 + 2 * kp + 1];
    } else {
      int gsel = d >> 6, dk = d & 63;
      int row = (w == 1 ? 0 : 128) + gsel * 64 + l;
      if (dk < 32) { v0 = Wih1[row * 64 + 2 * dk]; v1 = Wih1[row * 64 + 2 * dk + 1]; }
      else { int k = 2 * (dk - 32); v0 = Whh1[row * 64 + k]; v1 = Whh1[row * 64 + k + 1]; }
    }
  } else {
    int j = i - 24576, l = j >> 3, d = j & 7;
    int m = l >> 2, kq = l & 3, k = kq * 16 + 2 * d;
    v0 = Wlin[m * 64 + k]; v1 = Wlin[m * 64 + k + 1];
  }
  ws[i] = f16rne(v0) | (f16rne(v1) << 16);
}

#define DECLW32(wp)                                                            \
  u4 W0=(wp)[0],  W1=(wp)[1],  W2=(wp)[2],  W3=(wp)[3],                        \
     W4=(wp)[4],  W5=(wp)[5],  W6=(wp)[6],  W7=(wp)[7],                        \
     W8=(wp)[8],  W9=(wp)[9],  W10=(wp)[10],W11=(wp)[11],                      \
     W12=(wp)[12],W13=(wp)[13],W14=(wp)[14],W15=(wp)[15],                      \
     W16=(wp)[16],W17=(wp)[17],W18=(wp)[18],W19=(wp)[19],                      \
     W20=(wp)[20],W21=(wp)[21],W22=(wp)[22],W23=(wp)[23],                      \
     W24=(wp)[24],W25=(wp)[25],W26=(wp)[26],W27=(wp)[27],                      \
     W28=(wp)[28],W29=(wp)[29],W30=(wp)[30],W31=(wp)[31]

#define PINW8(a,b,c,d,e,f,g,h)                                                 \
  asm volatile("" : "+v"(a), "+v"(b), "+v"(c), "+v"(d),                        \
                    "+v"(e), "+v"(f), "+v"(g), "+v"(h))
#define PINALL() { PINW8(W0,W1,W2,W3,W4,W5,W6,W7);                             \
                   PINW8(W8,W9,W10,W11,W12,W13,W14,W15);                       \
                   PINW8(W16,W17,W18,W19,W20,W21,W22,W23);                     \
                   PINW8(W24,W25,W26,W27,W28,W29,W30,W31); }

__global__ __launch_bounds__(192)
__attribute__((amdgpu_waves_per_eu(1, 1)))
void rnn_fused(
    const float* __restrict__ y,
    const float* __restrict__ Wih0, const float* __restrict__ bih0,
    const float* __restrict__ bhh0,
    const float* __restrict__ bih1, const float* __restrict__ bhh1,
    const float* __restrict__ blin,
    const unsigned* __restrict__ ws,
    float* __restrict__ out)
{
  const int tid = threadIdx.x;
  // LDS: hb[buf][0:32)=h0 f16-pairs, [32:64)=h1 f16-pairs ; exb = (i,f) pairs
  __shared__ __align__(16) unsigned hb[128];
  __shared__ unsigned exb[64];
  if (tid < 128) hb[tid] = 0u;
  else exb[tid - 128] = 0u;
  __syncthreads();

  const u4* wp = (const u4*)(ws + tid * 128);

  if (tid < 64) {
    // ================= wave0: layer 0, all 4 gates per lane =================
    const int e = tid;
    DECLW32(wp);
    float bbi = bih0[e] + bhh0[e];
    float bbf = bih0[64 + e] + bhh0[64 + e];
    float bbg = bih0[128 + e] + bhh0[128 + e];
    float bbo = bih0[192 + e] + bhh0[192 + e];
    float wii = Wih0[e], wif = Wih0[64 + e], wig = Wih0[128 + e], wio = Wih0[192 + e];
    float c0 = 0.f;
    float yq0 = y[0], yq1 = y[1], yq2 = y[2], yq3 = y[3];

    #pragma unroll 1
    for (int s = 0; s < T + 2; ++s) {
      const int cur = s & 1, nxt = cur ^ 1;
      PINALL();
      if (s < T) {
        float y_nxt = (s + 4 < T) ? y[s + 4] : 0.f;
        const u4* hp = (const u4*)(hb + cur * 64);            // h0(s-1), 8 x b128
        u4 H0=hp[0],H1=hp[1],H2=hp[2],H3=hp[3],H4=hp[4],H5=hp[5],H6=hp[6],H7=hp[7];
        float ai0=0,ai1=0, af0=0,af1=0, ag0=0,ag1=0, ao0=0,ao1=0;
        DP4(ai0,W0,H0)  DP4(ai1,W1,H1)  DP4(ai0,W2,H2)  DP4(ai1,W3,H3)
        DP4(ai0,W4,H4)  DP4(ai1,W5,H5)  DP4(ai0,W6,H6)  DP4(ai1,W7,H7)
        DP4(af0,W8,H0)  DP4(af1,W9,H1)  DP4(af0,W10,H2) DP4(af1,W11,H3)
        DP4(af0,W12,H4) DP4(af1,W13,H5) DP4(af0,W14,H6) DP4(af1,W15,H7)
        DP4(ag0,W16,H0) DP4(ag1,W17,H1) DP4(ag0,W18,H2) DP4(ag1,W19,H3)
        DP4(ag0,W20,H4) DP4(ag1,W21,H5) DP4(ag0,W22,H6) DP4(ag1,W23,H7)
        DP4(ao0,W24,H0) DP4(ao1,W25,H1) DP4(ao0,W26,H2) DP4(ao1,W27,H3)
        DP4(ao0,W28,H4) DP4(ao1,W29,H5) DP4(ao0,W30,H6) DP4(ao1,W31,H7)
        float I = sigf((ai0 + ai1) + fmaf(yq0, wii, bbi));
        float F = sigf((af0 + af1) + fmaf(yq0, wif, bbf));
        float G = tanhf_((ag0 + ag1) + fmaf(yq0, wig, bbg));
        float O = sigf((ao0 + ao1) + fmaf(yq0, wio, bbo));
        c0 = fmaf(F, c0, I * G);
        float h = O * tanhf_(c0);
        float hp1 = DPPX1(h);                                  // partner h[e^1]
        unsigned pk = __builtin_bit_cast(unsigned, __builtin_amdgcn_cvt_pkrtz(h, hp1));
        if (!(e & 1)) hb[nxt * 64 + (e >> 1)] = pk;            // h0(s) f16-pairs
        yq0 = yq1; yq1 = yq2; yq2 = yq3; yq3 = y_nxt;
      }
      BARRIER();
      BARRIER();
    }
  } else if (tid < 128) {
    // ============ wave1: layer 1 gates i,f  +  head (phase 2) ============
    const int e = tid - 64;
    DECLW32(wp);
    const u4* hwp = (const u4*)(ws + 24576 + e * 8);
    u4 HW0 = hwp[0], HW1 = hwp[1];
    float bbA = bih1[e] + bhh1[e];                // gate i row e
    float bbB = bih1[64 + e] + bhh1[64 + e];      // gate f row 64+e
    const int m = e >> 2, kq = e & 3;
    float bl = (kq == 0) ? blin[m] : 0.f;

    #pragma unroll 1
    for (int s = 0; s < T + 2; ++s) {
      const int cur = s & 1;
      PINALL();
      if (s >= 1 && s <= T) {
        const u4* hp = (const u4*)(hb + cur * 64);            // h0(s-1)|h1(s-2)
        u4 H0=hp[0],H1=hp[1],H2=hp[2],H3=hp[3],H4=hp[4],H5=hp[5],H6=hp[6],H7=hp[7],
           H8=hp[8],H9=hp[9],H10=hp[10],H11=hp[11],H12=hp[12],H13=hp[13],H14=hp[14],H15=hp[15];
        float a0=0,a1=0,a2=0,a3=0, b0=0,b1=0,b2=0,b3=0;
        DP4(a0,W0,H0)   DP4(a1,W1,H1)   DP4(a2,W2,H2)   DP4(a3,W3,H3)
        DP4(a0,W4,H4)   DP4(a1,W5,H5)   DP4(a2,W6,H6)   DP4(a3,W7,H7)
        DP4(a0,W8,H8)   DP4(a1,W9,H9)   DP4(a2,W10,H10) DP4(a3,W11,H11)
        DP4(a0,W12,H12) DP4(a1,W13,H13) DP4(a2,W14,H14) DP4(a3,W15,H15)
        DP4(b0,W16,H0)  DP4(b1,W17,H1)  DP4(b2,W18,H2)  DP4(b3,W19,H3)
        DP4(b0,W20,H4)  DP4(b1,W21,H5)  DP4(b2,W22,H6)  DP4(b3,W23,H7)
        DP4(b0,W24,H8)  DP4(b1,W25,H9)  DP4(b2,W26,H10) DP4(b3,W27,H11)
        DP4(b0,W28,H12) DP4(b1,W29,H13) DP4(b2,W30,H14) DP4(b3,W31,H15)
        float I = sigf((a0 + a1) + (a2 + a3) + bbA);
        float F = sigf((b0 + b1) + (b2 + b3) + bbB);
        exb[e] = __builtin_bit_cast(unsigned, __builtin_amdgcn_cvt_pkrtz(I, F));
      }
      BARRIER();
      if (s >= 2) {                                            // head: out(s-2)
        const u4* h1p = (const u4*)(hb + cur * 64 + 32 + kq * 8);
        u4 X0 = h1p[0], X1 = h1p[1];
        float r2 = 0.f;
        DP4(r2, HW0, X0) DP4(r2, HW1, X1);
        r2 += DPPX1(r2);
        r2 += DPPX2(r2);                                       // sum over kq (quad)
        if (kq == 0) out[(s - 2) * 16 + m] = r2 + bl;
      }
      BARRIER();
    }
  } else {
    // ========== wave2: layer 1 gates g,o + c1/h1 update (phase 2) ==========
    const int e = tid - 128;
    DECLW32(wp);
    float bbG = bih1[128 + e] + bhh1[128 + e];    // gate g row 128+e
    float bbO = bih1[192 + e] + bhh1[192 + e];    // gate o row 192+e
    float c1 = 0.f, Gk = 0.f, Ok = 0.f;

    #pragma unroll 1
    for (int s = 0; s < T + 2; ++s) {
      const int cur = s & 1, nxt = cur ^ 1;
      PINALL();
      const bool act = (s >= 1 && s <= T);
      if (act) {
        const u4* hp = (const u4*)(hb + cur * 64);
        u4 H0=hp[0],H1=hp[1],H2=hp[2],H3=hp[3],H4=hp[4],H5=hp[5],H6=hp[6],H7=hp[7],
           H8=hp[8],H9=hp[9],H10=hp[10],H11=hp[11],H12=hp[12],H13=hp[13],H14=hp[14],H15=hp[15];
        float a0=0,a1=0,a2=0,a3=0, b0=0,b1=0,b2=0,b3=0;
        DP4(a0,W0,H0)   DP4(a1,W1,H1)   DP4(a2,W2,H2)   DP4(a3,W3,H3)
        DP4(a0,W4,H4)   DP4(a1,W5,H5)   DP4(a2,W6,H6)   DP4(a3,W7,H7)
        DP4(a0,W8,H8)   DP4(a1,W9,H9)   DP4(a2,W10,H10) DP4(a3,W11,H11)
        DP4(a0,W12,H12) DP4(a1,W13,H13) DP4(a2,W14,H14) DP4(a3,W15,H15)
        DP4(b0,W16,H0)  DP4(b1,W17,H1)  DP4(b2,W18,H2)  DP4(b3,W19,H3)
        DP4(b0,W20,H4)  DP4(b1,W21,H5)  DP4(b2,W22,H6)  DP4(b3,W23,H7)
        DP4(b0,W24,H8)  DP4(b1,W25,H9)  DP4(b2,W26,H10) DP4(b3,W27,H11)
        DP4(b0,W28,H12) DP4(b1,W29,H13) DP4(b2,W30,H14) DP4(b3,W31,H15)
        Gk = tanhf_((a0 + a1) + (a2 + a3) + bbG);
        Ok = sigf((b0 + b1) + (b2 + b3) + bbO);
      }
      BARRIER();
      if (act) {                                               // c/h for t = s-1
        h2v pif = __builtin_bit_cast(h2v, exb[e]);
        float I = (float)pif.x, F = (float)pif.y;
        c1 = fmaf(F, c1, I * Gk);
        float h = Ok * tanhf_(c1);
        float hp1 = DPPX1(h);
        unsigned pk = __builtin_bit_cast(unsigned, __builtin_amdgcn_cvt_pkrtz(h, hp1));
        if (!(e & 1)) hb[nxt * 64 + 32 + (e >> 1)] = pk;       // h1(s-1)
      }
      BARRIER();
    }
  }
}

extern "C" void kernel_launch(void* const* d_in, const int* in_sizes, int n_in,
                              void* d_out, int out_size, void* d_ws, size_t ws_size,
                              hipStream_t stream) {
  const float* y    = (const float*)d_in[0];
  const float* Wih0 = (const float*)d_in[1];
  const float* Whh0 = (const float*)d_in[2];
  const float* bih0 = (const float*)d_in[3];
  const float* bhh0 = (const float*)d_in[4];
  const float* Wih1 = (const float*)d_in[5];
  const float* Whh1 = (const float*)d_in[6];
  const float* bih1 = (const float*)d_in[7];
  const float* bhh1 = (const float*)d_in[8];
  const float* Wlin = (const float*)d_in[9];
  const float* blin = (const float*)d_in[10];
  unsigned* ws = (unsigned*)d_ws;                // 25088 dwords ~= 100 KB

  pack_w<<<dim3(98), dim3(256), 0, stream>>>(Whh0, Wih1, Whh1, Wlin, ws);
  rnn_fused<<<dim3(1), dim3(192), 0, stream>>>(
      y, Wih0, bih0, bhh0, bih1, bhh1, blin, ws, (float*)d_out);
}